// Round 1
// baseline (429.464 us; speedup 1.0000x reference)
//
#include <hip/hip_runtime.h>

#define N_PIX 4096
#define IMG_W 64
#define C_IN 256
#define TD3 768
#define N_B 8
#define N_G 64
#define C_OUT 256
#define KV_CHUNKS 4

// ---------------------------------------------------------------------------
// K1: qkv = W[768x256] * X[b][256x4096]  (1x1 conv as per-batch SGEMM, fp32)
// 128x128 tile, 8x8 micro-tile, BK=8
// ---------------------------------------------------------------------------
__global__ __launch_bounds__(256) void k_qkv(const float* __restrict__ x,
                                             const float* __restrict__ w,
                                             float* __restrict__ qkv) {
  __shared__ float As[8][132];
  __shared__ float Bs[8][128];
  const int t = threadIdx.x;
  const int n0 = blockIdx.x * 128;
  const int m0 = blockIdx.y * 128;
  const int b = blockIdx.z;
  const float* xb = x + (size_t)b * C_IN * N_PIX;
  float* cb = qkv + (size_t)b * TD3 * N_PIX;

  float acc[8][8];
#pragma unroll
  for (int i = 0; i < 8; i++)
#pragma unroll
    for (int j = 0; j < 8; j++) acc[i][j] = 0.f;

  const int tm = (t >> 4) * 8;
  const int tn = (t & 15) * 8;
  const int am = t >> 1, ak = (t & 1) * 4;
  const int bk = t >> 5, bn = (t & 31) * 4;

  for (int k0 = 0; k0 < C_IN; k0 += 8) {
    const float4 av = *(const float4*)(w + (size_t)(m0 + am) * C_IN + k0 + ak);
    const float4 bv = *(const float4*)(xb + (size_t)(k0 + bk) * N_PIX + n0 + bn);
    __syncthreads();
    As[ak + 0][am] = av.x;
    As[ak + 1][am] = av.y;
    As[ak + 2][am] = av.z;
    As[ak + 3][am] = av.w;
    *(float4*)(&Bs[bk][bn]) = bv;
    __syncthreads();
#pragma unroll
    for (int kk = 0; kk < 8; kk++) {
      const float4 a0 = *(const float4*)(&As[kk][tm]);
      const float4 a1 = *(const float4*)(&As[kk][tm + 4]);
      const float4 b0 = *(const float4*)(&Bs[kk][tn]);
      const float4 b1 = *(const float4*)(&Bs[kk][tn + 4]);
      const float a[8] = {a0.x, a0.y, a0.z, a0.w, a1.x, a1.y, a1.z, a1.w};
      const float bb[8] = {b0.x, b0.y, b0.z, b0.w, b1.x, b1.y, b1.z, b1.w};
#pragma unroll
      for (int i = 0; i < 8; i++)
#pragma unroll
        for (int j = 0; j < 8; j++) acc[i][j] = fmaf(a[i], bb[j], acc[i][j]);
    }
  }
#pragma unroll
  for (int i = 0; i < 8; i++) {
    float4 v0 = {acc[i][0], acc[i][1], acc[i][2], acc[i][3]};
    float4 v1 = {acc[i][4], acc[i][5], acc[i][6], acc[i][7]};
    float* p = cb + (size_t)(m0 + tm + i) * N_PIX + n0 + tn;
    *(float4*)(p) = v0;
    *(float4*)(p + 4) = v1;
  }
}

// ---------------------------------------------------------------------------
// K2: agg = grouped_pw_1x1( depthwise_5x5(qkv) )   fused
// one block per (b, pw-group g of 8 channels, 8x32 spatial tile)
// ---------------------------------------------------------------------------
__global__ __launch_bounds__(256) void k_agg(const float* __restrict__ qkv,
                                             const float* __restrict__ wdw,
                                             const float* __restrict__ wpw,
                                             float* __restrict__ agg) {
  __shared__ float sin_[8][12][36];  // 8 ch, 8+4 rows, 32+4 cols (halo 2)
  __shared__ float swd[200];         // 8 ch x 25 taps
  __shared__ float swp[64];          // 8 oc x 8 ic
  const int t = threadIdx.x;
  const int tx0 = blockIdx.x * 32;
  const int ty0 = blockIdx.y * 8;
  const int bg = blockIdx.z;
  const int b = bg / 96, g = bg % 96;
  const float* src = qkv + ((size_t)b * TD3 + g * 8) * N_PIX;

  if (t < 200) swd[t] = wdw[(size_t)g * 200 + t];
  if (t < 64) swp[t] = wpw[(size_t)g * 64 + t];

  for (int idx = t; idx < 8 * 12 * 36; idx += 256) {
    const int ch = idx / (12 * 36);
    const int r = idx % (12 * 36);
    const int iy = r / 36, ix = r % 36;
    const int y = ty0 + iy - 2, xx = tx0 + ix - 2;
    float v = 0.f;
    if (y >= 0 && y < IMG_W && xx >= 0 && xx < IMG_W)
      v = src[(size_t)ch * N_PIX + y * IMG_W + xx];
    sin_[ch][iy][ix] = v;
  }
  __syncthreads();

  const int py = t >> 5, px = t & 31;
  float dwv[8];
#pragma unroll
  for (int ch = 0; ch < 8; ch++) {
    float s = 0.f;
#pragma unroll
    for (int i = 0; i < 5; i++)
#pragma unroll
      for (int j = 0; j < 5; j++)
        s = fmaf(sin_[ch][py + i][px + j], swd[ch * 25 + i * 5 + j], s);
    dwv[ch] = s;
  }
  float* dst = agg + ((size_t)b * TD3 + g * 8) * N_PIX + (ty0 + py) * IMG_W + tx0 + px;
#pragma unroll
  for (int oc = 0; oc < 8; oc++) {
    float s = 0.f;
#pragma unroll
    for (int ic = 0; ic < 8; ic++) s = fmaf(dwv[ic], swp[oc * 8 + ic], s);
    dst[(size_t)oc * N_PIX] = s;
  }
}

// ---------------------------------------------------------------------------
// K3: kv[c][b][g][d][e] partials = sum_{n in chunk c} relu(k[n,d]) * vext[n,e]
// grid (KV_CHUNKS, 64, 8); deterministic chunk-partial store (no atomics)
// ---------------------------------------------------------------------------
__global__ __launch_bounds__(256) void k_kv(const float* __restrict__ qkv,
                                            const float* __restrict__ agg,
                                            float* __restrict__ kvbuf) {
  const int t = threadIdx.x;
  const int chunk = blockIdx.x;
  const int g = blockIdx.y;
  const int b = blockIdx.z;
  const float* src = (g < 32) ? qkv : agg;
  const int base = (g < 32 ? g : g - 32) * 24;
  const float* kc = src + ((size_t)b * TD3 + base + 8) * N_PIX;
  const float* vc = src + ((size_t)b * TD3 + base + 16) * N_PIX;

  float acc[72];
#pragma unroll
  for (int i = 0; i < 72; i++) acc[i] = 0.f;

  const int n0 = chunk * (N_PIX / KV_CHUNKS);
  for (int i = 0; i < (N_PIX / KV_CHUNKS) / 256; i++) {
    const int n = n0 + t + i * 256;
    float kd[8], ve[8];
#pragma unroll
    for (int d = 0; d < 8; d++) kd[d] = fmaxf(kc[(size_t)d * N_PIX + n], 0.f);
#pragma unroll
    for (int e = 0; e < 8; e++) ve[e] = vc[(size_t)e * N_PIX + n];
#pragma unroll
    for (int d = 0; d < 8; d++) {
#pragma unroll
      for (int e = 0; e < 8; e++) acc[d * 9 + e] = fmaf(kd[d], ve[e], acc[d * 9 + e]);
      acc[d * 9 + 8] += kd[d];
    }
  }
  // wave (64-lane) reduce each of the 72 accumulators
#pragma unroll
  for (int i = 0; i < 72; i++) {
    float v = acc[i];
#pragma unroll
    for (int off = 32; off > 0; off >>= 1) v += __shfl_down(v, off, 64);
    acc[i] = v;
  }
  __shared__ float red[4][72];
  const int lane = t & 63, wv = t >> 6;
  if (lane == 0) {
#pragma unroll
    for (int i = 0; i < 72; i++) red[wv][i] = acc[i];
  }
  __syncthreads();
  if (t < 72) {
    const float s = red[0][t] + red[1][t] + red[2][t] + red[3][t];
    kvbuf[(((size_t)chunk * N_B + b) * N_G + g) * 72 + t] = s;
  }
}

// ---------------------------------------------------------------------------
// K4: fused attention-out + proj GEMM.
// Block = (b, 64-pixel tile). The A-panel (512 attn channels x 64 px) is
// computed group-by-group on the fly from q and the LDS-resident kv matrices.
// ---------------------------------------------------------------------------
__global__ __launch_bounds__(256) void k_out(const float* __restrict__ qkv,
                                             const float* __restrict__ agg,
                                             const float* __restrict__ kvbuf,
                                             const float* __restrict__ wproj,
                                             float* __restrict__ out) {
  __shared__ float skv[N_G][72];
  __shared__ float sq[8][64];
  __shared__ float sa[8][68];
  __shared__ float sw[8][256];
  const int t = threadIdx.x;
  const int n0 = blockIdx.x * 64;
  const int b = blockIdx.y;

  // load + chunk-sum kv matrices for this batch
  for (int idx = t; idx < N_G * 72; idx += 256) {
    float s = 0.f;
#pragma unroll
    for (int c = 0; c < KV_CHUNKS; c++)
      s += kvbuf[(((size_t)c * N_B + b) * N_G) * 72 + idx];
    skv[idx / 72][idx % 72] = s;
  }

  float acc[8][8];
#pragma unroll
  for (int i = 0; i < 8; i++)
#pragma unroll
    for (int j = 0; j < 8; j++) acc[i][j] = 0.f;

  const int roc = (t & 31) * 8;    // 8 output channels per thread
  const int colpx = (t >> 5) * 8;  // 8 pixels per thread
  __syncthreads();

  for (int g = 0; g < N_G; g++) {
    const float* src = (g < 32) ? qkv : agg;
    const int base = (g < 32 ? g : g - 32) * 24;
    // stage relu(q): 8 ch x 64 px
    {
      const int j = t >> 5, px = t & 31;
      const float* qc = src + ((size_t)b * TD3 + base + j) * N_PIX + n0;
      sq[j][px] = fmaxf(qc[px], 0.f);
      sq[j][px + 32] = fmaxf(qc[px + 32], 0.f);
    }
    // stage w_proj chunk: sw[kk][oc] = wproj[oc][g*8+kk]
    {
      const float* wp = wproj + (size_t)t * 512 + g * 8;
      const float4 w0 = *(const float4*)(wp);
      const float4 w1 = *(const float4*)(wp + 4);
      sw[0][t] = w0.x; sw[1][t] = w0.y; sw[2][t] = w0.z; sw[3][t] = w0.w;
      sw[4][t] = w1.x; sw[5][t] = w1.y; sw[6][t] = w1.z; sw[7][t] = w1.w;
    }
    __syncthreads();
    // attention rows: sa[e][px] = (q . kv[:,e]) / (q . kv[:,8] + eps)
    {
      const int e = t >> 5;
      const int px0 = t & 31;
      const float* kvg = skv[g];
#pragma unroll
      for (int r = 0; r < 2; r++) {
        const int px = px0 + r * 32;
        float num = 0.f, den = 0.f;
#pragma unroll
        for (int d = 0; d < 8; d++) {
          const float qd = sq[d][px];
          num = fmaf(qd, kvg[d * 9 + e], num);
          den = fmaf(qd, kvg[d * 9 + 8], den);
        }
        sa[e][px] = num / (den + 1e-15f);
      }
    }
    __syncthreads();
    // GEMM accumulate: acc[oc][px] += sw[kk][oc] * sa[kk][px]
#pragma unroll
    for (int kk = 0; kk < 8; kk++) {
      const float4 w0 = *(const float4*)(&sw[kk][roc]);
      const float4 w1 = *(const float4*)(&sw[kk][roc + 4]);
      const float4 a0 = *(const float4*)(&sa[kk][colpx]);
      const float4 a1 = *(const float4*)(&sa[kk][colpx + 4]);
      const float wv[8] = {w0.x, w0.y, w0.z, w0.w, w1.x, w1.y, w1.z, w1.w};
      const float av[8] = {a0.x, a0.y, a0.z, a0.w, a1.x, a1.y, a1.z, a1.w};
#pragma unroll
      for (int i = 0; i < 8; i++)
#pragma unroll
        for (int j = 0; j < 8; j++) acc[i][j] = fmaf(wv[i], av[j], acc[i][j]);
    }
    __syncthreads();
  }
#pragma unroll
  for (int i = 0; i < 8; i++) {
    float4 v0 = {acc[i][0], acc[i][1], acc[i][2], acc[i][3]};
    float4 v1 = {acc[i][4], acc[i][5], acc[i][6], acc[i][7]};
    float* p = out + ((size_t)b * C_OUT + roc + i) * N_PIX + n0 + colpx;
    *(float4*)(p) = v0;
    *(float4*)(p + 4) = v1;
  }
}

// ---------------------------------------------------------------------------
extern "C" void kernel_launch(void* const* d_in, const int* in_sizes, int n_in,
                              void* d_out, int out_size, void* d_ws, size_t ws_size,
                              hipStream_t stream) {
  const float* x = (const float*)d_in[0];
  const float* w_qkv = (const float*)d_in[1];
  const float* w_dw = (const float*)d_in[2];
  const float* w_pw = (const float*)d_in[3];
  const float* w_proj = (const float*)d_in[4];
  float* out = (float*)d_out;

  float* qkv = (float*)d_ws;                       // 8*768*4096 f32 = 96 MB
  float* agg = qkv + (size_t)N_B * TD3 * N_PIX;    // 96 MB
  float* kvbuf = agg + (size_t)N_B * TD3 * N_PIX;  // 4*8*64*72 f32 = 0.6 MB

  k_qkv<<<dim3(N_PIX / 128, TD3 / 128, N_B), 256, 0, stream>>>(x, w_qkv, qkv);
  k_agg<<<dim3(2, 8, N_B * 96), 256, 0, stream>>>(qkv, w_dw, w_pw, agg);
  k_kv<<<dim3(KV_CHUNKS, N_G, N_B), 256, 0, stream>>>(qkv, agg, kvbuf);
  k_out<<<dim3(N_PIX / 64, N_B), 256, 0, stream>>>(qkv, agg, kvbuf, w_proj, out);
}

// Round 2
// 256.947 us; speedup vs baseline: 1.6714x; 1.6714x over previous
//
#include <hip/hip_runtime.h>

#define N_PIX 4096
#define IMG_W 64
#define C_IN 256
#define TD3 768
#define N_B 8
#define N_G 64
#define C_OUT 256
#define KV_CHUNKS 4

typedef _Float16 f16;
typedef _Float16 half8 __attribute__((ext_vector_type(8)));
typedef float f32x4 __attribute__((ext_vector_type(4)));

// ---------------------------------------------------------------------------
// k_cvt: fp32 -> (hi, lo) f16 planes, same layout (for weights)
// ---------------------------------------------------------------------------
__global__ __launch_bounds__(256) void k_cvt(const float* __restrict__ a,
                                             f16* __restrict__ h,
                                             f16* __restrict__ l, int n) {
  const int i = blockIdx.x * 256 + threadIdx.x;
  if (i < n) {
    const float v = a[i];
    const f16 x = (f16)v;
    h[i] = x;
    l[i] = (f16)(v - (float)x);
  }
}

// ---------------------------------------------------------------------------
// k_xT: x[b][256][4096] fp32 -> xT[b][4096][256] (hi,lo) f16  (64x64 LDS tile)
// ---------------------------------------------------------------------------
__global__ __launch_bounds__(256) void k_xT(const float* __restrict__ x,
                                            f16* __restrict__ xh,
                                            f16* __restrict__ xl) {
  __shared__ float st[64][65];
  const int t = threadIdx.x;
  const int n0 = blockIdx.x * 64;
  const int k0 = blockIdx.y * 64;
  const size_t b = blockIdx.z;
  const float* xb = x + b * (size_t)C_IN * N_PIX;
#pragma unroll
  for (int i = 0; i < 16; ++i) {
    const int idx = t + i * 256;
    const int r = idx >> 6, c = idx & 63;
    st[r][c] = xb[(size_t)(k0 + r) * N_PIX + n0 + c];
  }
  __syncthreads();
#pragma unroll
  for (int i = 0; i < 16; ++i) {
    const int idx = t + i * 256;
    const int n = idx >> 6, k = idx & 63;
    const float v = st[k][n];
    const f16 h = (f16)v;
    const size_t o = (b * N_PIX + n0 + n) * C_IN + k0 + k;
    xh[o] = h;
    xl[o] = (f16)(v - (float)h);
  }
}

// ---------------------------------------------------------------------------
// k_gemm: C[b][M][4096] = A[M][K] * B[b][K][4096], split-f16 MFMA.
// A given row-major [M][K] (hi,lo); B given TRANSPOSED [b][4096][K] (hi,lo).
// 128x128 tile, 4 waves (2x2 of 64x64), BK=32, fragment-major LDS slabs
// filled by global_load_lds(16B) with per-lane global addresses.
// ---------------------------------------------------------------------------
template <typename OutT>
__global__ __launch_bounds__(256) void k_gemm(const f16* __restrict__ Ah,
                                              const f16* __restrict__ Al,
                                              const f16* __restrict__ Bh,
                                              const f16* __restrict__ Bl,
                                              OutT* __restrict__ C,
                                              int M, int K) {
  __shared__ f16 sm[32 * 512];  // 32 slabs x 1KB: [A hi 0-7][A lo 8-15][B hi][B lo]
  const int t = threadIdx.x;
  const int lane = t & 63;
  const int w = t >> 6;
  const int n0 = blockIdx.x * 128;
  const int m0 = blockIdx.y * 128;
  const size_t bz = blockIdx.z;
  const f16* Bhb = Bh + bz * (size_t)N_PIX * K;
  const f16* Blb = Bl + bz * (size_t)N_PIX * K;
  OutT* Cb = C + bz * (size_t)M * N_PIX;

  f32x4 acc[4][4];
#pragma unroll
  for (int i = 0; i < 4; ++i)
#pragma unroll
    for (int j = 0; j < 4; ++j) acc[i][j] = (f32x4){0.f, 0.f, 0.f, 0.f};

  const int wm = w >> 1, wn = w & 1;
  const int fr = lane & 15;        // row within 16-row fragment
  const int fk = (lane >> 4) * 8;  // k-octet within BK=32

  for (int k0 = 0; k0 < K; k0 += 32) {
    __syncthreads();
#pragma unroll
    for (int i = 0; i < 8; ++i) {
      const int s = w + i * 4;  // slab 0..31, round-robin across waves
      const int frag = s & 7;
      const f16* base;
      int row0;
      if (s < 8) {
        base = Ah; row0 = m0;
      } else if (s < 16) {
        base = Al; row0 = m0;
      } else if (s < 24) {
        base = Bhb; row0 = n0;
      } else {
        base = Blb; row0 = n0;
      }
      const f16* g = base + (size_t)(row0 + frag * 16 + fr) * K + k0 + fk;
      __builtin_amdgcn_global_load_lds(
          (const __attribute__((address_space(1))) unsigned int*)g,
          (__attribute__((address_space(3))) unsigned int*)&sm[s * 512], 16, 0, 0);
    }
    __syncthreads();
    half8 ah[4], al[4], bh[4], bl[4];
#pragma unroll
    for (int mi = 0; mi < 4; ++mi) {
      ah[mi] = *(const half8*)&sm[(wm * 4 + mi) * 512 + lane * 8];
      al[mi] = *(const half8*)&sm[(8 + wm * 4 + mi) * 512 + lane * 8];
    }
#pragma unroll
    for (int ni = 0; ni < 4; ++ni) {
      bh[ni] = *(const half8*)&sm[(16 + wn * 4 + ni) * 512 + lane * 8];
      bl[ni] = *(const half8*)&sm[(24 + wn * 4 + ni) * 512 + lane * 8];
    }
#pragma unroll
    for (int mi = 0; mi < 4; ++mi)
#pragma unroll
      for (int ni = 0; ni < 4; ++ni) {
        acc[mi][ni] = __builtin_amdgcn_mfma_f32_16x16x32_f16(ah[mi], bh[ni], acc[mi][ni], 0, 0, 0);
        acc[mi][ni] = __builtin_amdgcn_mfma_f32_16x16x32_f16(ah[mi], bl[ni], acc[mi][ni], 0, 0, 0);
        acc[mi][ni] = __builtin_amdgcn_mfma_f32_16x16x32_f16(al[mi], bh[ni], acc[mi][ni], 0, 0, 0);
      }
  }
  const int cr = (lane >> 4) * 4;
  const int cc = lane & 15;
#pragma unroll
  for (int mi = 0; mi < 4; ++mi)
#pragma unroll
    for (int ni = 0; ni < 4; ++ni) {
      OutT* p = Cb + (size_t)(m0 + wm * 64 + mi * 16 + cr) * N_PIX + n0 + wn * 64 + ni * 16 + cc;
#pragma unroll
      for (int r = 0; r < 4; ++r) p[(size_t)r * N_PIX] = (OutT)acc[mi][ni][r];
    }
}

// ---------------------------------------------------------------------------
// k_agg: agg = grouped_pw_1x1( depthwise_5x5(qkv) ), f16 in/out, fp32 math
// ---------------------------------------------------------------------------
__global__ __launch_bounds__(256) void k_agg(const f16* __restrict__ qkv,
                                             const float* __restrict__ wdw,
                                             const float* __restrict__ wpw,
                                             f16* __restrict__ agg) {
  __shared__ float sin_[8][12][36];
  __shared__ float swd[200];
  __shared__ float swp[64];
  const int t = threadIdx.x;
  const int tx0 = blockIdx.x * 32;
  const int ty0 = blockIdx.y * 8;
  const int bg = blockIdx.z;
  const int b = bg / 96, g = bg % 96;
  const f16* src = qkv + ((size_t)b * TD3 + g * 8) * N_PIX;

  if (t < 200) swd[t] = wdw[(size_t)g * 200 + t];
  if (t < 64) swp[t] = wpw[(size_t)g * 64 + t];

  for (int idx = t; idx < 8 * 12 * 36; idx += 256) {
    const int ch = idx / (12 * 36);
    const int r = idx % (12 * 36);
    const int iy = r / 36, ix = r % 36;
    const int y = ty0 + iy - 2, xx = tx0 + ix - 2;
    float v = 0.f;
    if (y >= 0 && y < IMG_W && xx >= 0 && xx < IMG_W)
      v = (float)src[(size_t)ch * N_PIX + y * IMG_W + xx];
    sin_[ch][iy][ix] = v;
  }
  __syncthreads();

  const int py = t >> 5, px = t & 31;
  float dwv[8];
#pragma unroll
  for (int ch = 0; ch < 8; ch++) {
    float s = 0.f;
#pragma unroll
    for (int i = 0; i < 5; i++)
#pragma unroll
      for (int j = 0; j < 5; j++)
        s = fmaf(sin_[ch][py + i][px + j], swd[ch * 25 + i * 5 + j], s);
    dwv[ch] = s;
  }
  f16* dst = agg + ((size_t)b * TD3 + g * 8) * N_PIX + (ty0 + py) * IMG_W + tx0 + px;
#pragma unroll
  for (int oc = 0; oc < 8; oc++) {
    float s = 0.f;
#pragma unroll
    for (int ic = 0; ic < 8; ic++) s = fmaf(dwv[ic], swp[oc * 8 + ic], s);
    dst[(size_t)oc * N_PIX] = (f16)s;
  }
}

// ---------------------------------------------------------------------------
// k_kv: chunked kv partial sums (deterministic), f16 in, fp32 accumulate
// ---------------------------------------------------------------------------
__global__ __launch_bounds__(256) void k_kv(const f16* __restrict__ qkv,
                                            const f16* __restrict__ agg,
                                            float* __restrict__ kvbuf) {
  const int t = threadIdx.x;
  const int chunk = blockIdx.x;
  const int g = blockIdx.y;
  const int b = blockIdx.z;
  const f16* src = (g < 32) ? qkv : agg;
  const int base = (g & 31) * 24;
  const f16* kc = src + ((size_t)b * TD3 + base + 8) * N_PIX;
  const f16* vc = src + ((size_t)b * TD3 + base + 16) * N_PIX;

  float acc[72];
#pragma unroll
  for (int i = 0; i < 72; i++) acc[i] = 0.f;

  const int n0 = chunk * (N_PIX / KV_CHUNKS);
  for (int i = 0; i < (N_PIX / KV_CHUNKS) / 256; i++) {
    const int n = n0 + t + i * 256;
    float kd[8], ve[8];
#pragma unroll
    for (int d = 0; d < 8; d++) kd[d] = fmaxf((float)kc[(size_t)d * N_PIX + n], 0.f);
#pragma unroll
    for (int e = 0; e < 8; e++) ve[e] = (float)vc[(size_t)e * N_PIX + n];
#pragma unroll
    for (int d = 0; d < 8; d++) {
#pragma unroll
      for (int e = 0; e < 8; e++) acc[d * 9 + e] = fmaf(kd[d], ve[e], acc[d * 9 + e]);
      acc[d * 9 + 8] += kd[d];
    }
  }
#pragma unroll
  for (int i = 0; i < 72; i++) {
    float v = acc[i];
#pragma unroll
    for (int off = 32; off > 0; off >>= 1) v += __shfl_down(v, off, 64);
    acc[i] = v;
  }
  __shared__ float red[4][72];
  const int lane = t & 63, wv = t >> 6;
  if (lane == 0) {
#pragma unroll
    for (int i = 0; i < 72; i++) red[wv][i] = acc[i];
  }
  __syncthreads();
  if (t < 72) {
    const float s = red[0][t] + red[1][t] + red[2][t] + red[3][t];
    kvbuf[(((size_t)chunk * N_B + b) * N_G + g) * 72 + t] = s;
  }
}

// ---------------------------------------------------------------------------
// k_kvsum: sum the 4 chunk partials -> kvsum[b][g][72]
// ---------------------------------------------------------------------------
__global__ __launch_bounds__(256) void k_kvsum(const float* __restrict__ kvbuf,
                                               float* __restrict__ kvsum) {
  const int i = blockIdx.x * 256 + threadIdx.x;  // < 8*64*72 = 36864
  float s = 0.f;
#pragma unroll
  for (int c = 0; c < KV_CHUNKS; c++) s += kvbuf[(size_t)c * (N_B * N_G * 72) + i];
  kvsum[i] = s;
}

// ---------------------------------------------------------------------------
// k_att: att^T[b][4096][512] (hi,lo) f16 = attention channels, transposed.
// Block = (32 px, b). Per thread: 1 px, 8 groups. LDS-staged coalesced writes.
// ---------------------------------------------------------------------------
__global__ __launch_bounds__(256) void k_att(const f16* __restrict__ qkvh,
                                             const f16* __restrict__ aggh,
                                             const float* __restrict__ kvsum,
                                             f16* __restrict__ atth,
                                             f16* __restrict__ attl) {
  __shared__ float skv[N_G * 72];
  __shared__ f16 sa[512][34];  // padded: stride 68B = 17 banks -> conflict-free
  const int t = threadIdx.x;
  const int n0 = blockIdx.x * 32;
  const size_t b = blockIdx.y;
  for (int i = t; i < N_G * 72; i += 256) skv[i] = kvsum[b * (N_G * 72) + i];
  __syncthreads();
  const int px = t & 31, gq = t >> 5;
  float att[8][8];
#pragma unroll
  for (int gi = 0; gi < 8; ++gi) {
    const int g = gq * 8 + gi;
    const f16* src = (g < 32) ? qkvh : aggh;
    const int base = (g & 31) * 24;
    const f16* qc = src + ((size_t)b * TD3 + base) * N_PIX + n0 + px;
    float num[8] = {0.f, 0.f, 0.f, 0.f, 0.f, 0.f, 0.f, 0.f};
    float den = 0.f;
#pragma unroll
    for (int d = 0; d < 8; ++d) {
      const float qd = fmaxf((float)qc[(size_t)d * N_PIX], 0.f);
      const float* kvg = &skv[g * 72 + d * 9];
#pragma unroll
      for (int e = 0; e < 8; ++e) num[e] = fmaf(qd, kvg[e], num[e]);
      den = fmaf(qd, kvg[8], den);
    }
    const float rd = 1.f / (den + 1e-15f);
#pragma unroll
    for (int e = 0; e < 8; ++e) att[gi][e] = num[e] * rd;
  }
#pragma unroll
  for (int gi = 0; gi < 8; ++gi)
#pragma unroll
    for (int e = 0; e < 8; ++e) sa[(gq * 8 + gi) * 8 + e][px] = (f16)att[gi][e];
  __syncthreads();
  {
    f16* dst = atth + (b * N_PIX + n0) * 512;
    for (int i = 0; i < 64; ++i) {
      const int idx = t + i * 256;
      dst[idx] = sa[idx & 511][idx >> 9];
    }
  }
  __syncthreads();
#pragma unroll
  for (int gi = 0; gi < 8; ++gi)
#pragma unroll
    for (int e = 0; e < 8; ++e) {
      const float v = att[gi][e];
      const f16 h = (f16)v;
      sa[(gq * 8 + gi) * 8 + e][px] = (f16)(v - (float)h);
    }
  __syncthreads();
  {
    f16* dst = attl + (b * N_PIX + n0) * 512;
    for (int i = 0; i < 64; ++i) {
      const int idx = t + i * 256;
      dst[idx] = sa[idx & 511][idx >> 9];
    }
  }
}

// ---------------------------------------------------------------------------
extern "C" void kernel_launch(void* const* d_in, const int* in_sizes, int n_in,
                              void* d_out, int out_size, void* d_ws, size_t ws_size,
                              hipStream_t stream) {
  const float* x = (const float*)d_in[0];
  const float* w_qkv = (const float*)d_in[1];
  const float* w_dw = (const float*)d_in[2];
  const float* w_pw = (const float*)d_in[3];
  const float* w_proj = (const float*)d_in[4];
  float* out = (float*)d_out;

  char* ws = (char*)d_ws;
  size_t off = 0;
  f16* qkvh = (f16*)(ws + off); off += (size_t)N_B * TD3 * N_PIX * 2;          // 50.3 MB
  f16* aggh = (f16*)(ws + off); off += (size_t)N_B * TD3 * N_PIX * 2;          // 50.3 MB
  float* kvbuf = (float*)(ws + off); off += (size_t)KV_CHUNKS * N_B * N_G * 72 * 4;
  float* kvsum = (float*)(ws + off); off += (size_t)N_B * N_G * 72 * 4;
  f16* wqh = (f16*)(ws + off); off += (size_t)TD3 * C_IN * 2;
  f16* wql = (f16*)(ws + off); off += (size_t)TD3 * C_IN * 2;
  f16* wph = (f16*)(ws + off); off += (size_t)C_OUT * 512 * 2;
  f16* wpl = (f16*)(ws + off); off += (size_t)C_OUT * 512 * 2;
  // xT region is dead after the qkv GEMM; attT overlays it.
  f16* xTh = (f16*)(ws + off);
  f16* xTl = xTh + (size_t)N_B * N_PIX * C_IN;
  f16* atth = (f16*)(ws + off);
  f16* attl = atth + (size_t)N_B * N_PIX * 512;

  k_cvt<<<dim3((TD3 * C_IN + 255) / 256), 256, 0, stream>>>(w_qkv, wqh, wql, TD3 * C_IN);
  k_cvt<<<dim3((C_OUT * 512 + 255) / 256), 256, 0, stream>>>(w_proj, wph, wpl, C_OUT * 512);
  k_xT<<<dim3(N_PIX / 64, C_IN / 64, N_B), 256, 0, stream>>>(x, xTh, xTl);
  k_gemm<f16><<<dim3(N_PIX / 128, TD3 / 128, N_B), 256, 0, stream>>>(
      wqh, wql, xTh, xTl, qkvh, TD3, C_IN);
  k_agg<<<dim3(2, 8, N_B * 96), 256, 0, stream>>>(qkvh, w_dw, w_pw, aggh);
  k_kv<<<dim3(KV_CHUNKS, N_G, N_B), 256, 0, stream>>>(qkvh, aggh, kvbuf);
  k_kvsum<<<dim3(N_B * N_G * 72 / 256), 256, 0, stream>>>(kvbuf, kvsum);
  k_att<<<dim3(N_PIX / 32, N_B), 256, 0, stream>>>(qkvh, aggh, kvsum, atth, attl);
  k_gemm<float><<<dim3(N_PIX / 128, C_OUT / 128, N_B), 256, 0, stream>>>(
      wph, wpl, atth, attl, out, C_OUT, 512);
}